// Round 4
// baseline (602.050 us; speedup 1.0000x reference)
//
#include <hip/hip_runtime.h>
#include <math.h>

#define T_ 4
#define B_ 16
#define C_ 384
#define N_ 1024
#define CN_ (C_ * N_)      // 393216
#define BCN_ (B_ * CN_)    // 6291456
#define TBCN_ (T_ * BCN_)  // 25165824
#define HEADS_ 8
#define DH_ 48
#define EPS_ 1e-5f
#define NW_ 12             // 384 bits -> 12 words per column
#define M3_ 1152           // 3*C_

typedef float f4 __attribute__((ext_vector_type(4)));
typedef float f2 __attribute__((ext_vector_type(2)));

// ===========================================================================
// Mask bit-layout (PERMUTED, branch-local, identical for q,k,v; used for
// mask_q/mask_k/mask_v, kvw, cnt, Wtp):
// Within a branch (384 channels), lane l owns local channels
//   c = 4l + q      (q=0..3, the f4 group, c in [0,256))
//   c = 256 + 2l + q (q=0..1, the f2 group, c in [256,384))
// Ballots -> words:
//   f4 q: lo -> word 2q,   hi -> word 2q+1    (h = lane>>5, bit i = lane&31)
//   f2 q: lo -> word 8+2q, hi -> word 9+2q
// Forward decode (word Wb, bit i) -> local channel (used by prep_wt_proj):
//   Wb<8 : c = 128*(Wb&1) + 4*i + (Wb>>1)
//   Wb>=8: c = 256 + 64*((Wb-8)&1) + 2*i + ((Wb-8)>>1)
// Inverse (channel -> word,bit) (used by v_to_out1):
//   c<256 : Wb = 2*(c&3) + (c>>7),            bit = (c&127)>>2
//   c>=256: r=c-256; Wb = 8+2*(r&1)+(r>>6),   bit = (r&63)>>1
// mask_x (input side) keeps the plain layout: word w, bit i <-> c = 32w+i.
// ===========================================================================

// ---------------------------------------------------------------------------
// P1: Wt_qkv[c][br*384+m] = W_br[m][c]   (concat q,k,v, transposed)
// ---------------------------------------------------------------------------
__global__ __launch_bounds__(256) void prep_wt_qkv(
        const float* __restrict__ qw, const float* __restrict__ kw,
        const float* __restrict__ vw, float* __restrict__ Wt) {
    int idx = blockIdx.x * 256 + threadIdx.x;  // over 384*384
    int m = idx / C_, c = idx % C_;
    Wt[(size_t)c * M3_ + m]       = qw[idx];
    Wt[(size_t)c * M3_ + 384 + m] = kw[idx];
    Wt[(size_t)c * M3_ + 768 + m] = vw[idx];
}

// Wtp rows in PERMUTED q-storage order: row r holds proj_w[:, creal(r)]^T
__global__ __launch_bounds__(256) void prep_wt_proj(
        const float* __restrict__ pw, float* __restrict__ Wtp) {
    int idx = blockIdx.x * 256 + threadIdx.x;   // over 384*384
    int r = idx / C_, m = idx % C_;
    int Wb = r >> 5, i = r & 31;
    int c = (Wb < 8) ? (128 * (Wb & 1) + 4 * i + (Wb >> 1))
                     : (256 + 64 * ((Wb - 8) & 1) + 2 * i + ((Wb - 8) >> 1));
    Wtp[(size_t)r * C_ + m] = pw[(size_t)m * C_ + c];
}

// ---------------------------------------------------------------------------
// P2: per-m' BN constants for qkv branches (inv computed exactly as reference)
// ---------------------------------------------------------------------------
__global__ __launch_bounds__(256) void prep_bn(
        const float* __restrict__ qg, const float* __restrict__ qb,
        const float* __restrict__ qm, const float* __restrict__ qv,
        const float* __restrict__ kg, const float* __restrict__ kb,
        const float* __restrict__ km, const float* __restrict__ kv2,
        const float* __restrict__ vg, const float* __restrict__ vb,
        const float* __restrict__ vm, const float* __restrict__ vv,
        float* __restrict__ invA, float* __restrict__ muA, float* __restrict__ beA) {
    int i = blockIdx.x * 256 + threadIdx.x;
    if (i >= M3_) return;
    int br = i / C_, c = i % C_;
    const float *g, *bb, *mm, *va;
    if (br == 0)      { g = qg; bb = qb; mm = qm; va = qv; }
    else if (br == 1) { g = kg; bb = kb; mm = km; va = kv2; }
    else              { g = vg; bb = vb; mm = vm; va = vv; }
    invA[i] = g[c] / sqrtf(va[c] + EPS_);
    muA[i]  = mm[c];
    beA[i]  = bb[c];
}

// ---------------------------------------------------------------------------
// K1: shortcut LIF on x -> column bitmasks  mask_x[t][b][w][n]  (plain layout)
// ---------------------------------------------------------------------------
__global__ __launch_bounds__(256) void lif_x_mask(const float* __restrict__ x,
                                                  unsigned* __restrict__ mask_x) {
    int n  = blockIdx.x * 256 + threadIdx.x;
    int cw = blockIdx.y;   // 0..11
    int b  = blockIdx.z;   // 0..15
    unsigned wrd[T_] = {0u, 0u, 0u, 0u};
    const float* xb = x + (size_t)b * CN_ + (size_t)cw * 32 * N_ + n;
#pragma unroll 4
    for (int cb = 0; cb < 32; ++cb) {
        const float* xp = xb + (size_t)cb * N_;
        float v = 0.f;
#pragma unroll
        for (int t = 0; t < T_; ++t) {
            float xt = xp[(size_t)t * BCN_];
            v = v + (xt - v) * 0.5f;   // == v + (x - v)/2 exactly
            if (v >= 1.0f) { wrd[t] |= (1u << cb); v = 0.f; }
        }
    }
#pragma unroll
    for (int t = 0; t < T_; ++t)
        mask_x[((size_t)(t * B_ + b) * NW_ + cw) * N_ + n] = wrd[t];
}

// ---------------------------------------------------------------------------
// K3: fused sparse QKV GEMM + BN + LIF -> spike bitmasks (permuted layout)
// Wave = (column, BRANCH): 3x the waves of the previous version. Each wave
// covers 384 outputs (f4 @ 4*lane, f2 @ 256+2*lane), so per active bit only
// 2 vector loads (16B+8B per lane); bits processed 4-deep (8 loads in
// flight). Adds strictly sequential in ascending c -> spike decisions
// bit-identical to the previous passing kernel.
// ---------------------------------------------------------------------------
__global__ __launch_bounds__(256) void qkv_sparse(
        const unsigned* __restrict__ mask_x, const float* __restrict__ Wt,
        const float* __restrict__ invA, const float* __restrict__ muA,
        const float* __restrict__ beA,
        unsigned* __restrict__ mq, unsigned* __restrict__ mk,
        unsigned* __restrict__ mv) {
    const int lane = threadIdx.x & 63;
    const int col  = threadIdx.x >> 6;   // 0..3
    const int n = blockIdx.x * 4 + col;
    const int b = blockIdx.y;
    const int br = blockIdx.z;           // 0=q, 1=k, 2=v

    const int cb4 = 4 * lane;            // f4 local channels base
    const int cb2 = 256 + 2 * lane;      // f2 local channels base
    const int boff = br * C_;            // branch offset within 1152-wide row

    // BN constants, loop-invariant (linear channel index = boff + local c)
    f4 iv4 = *(const f4*)(invA + boff + cb4);
    f4 mu4 = *(const f4*)(muA + boff + cb4);
    f4 be4 = *(const f4*)(beA + boff + cb4);
    f2 iv2 = *(const f2*)(invA + boff + cb2);
    f2 mu2 = *(const f2*)(muA + boff + cb2);
    f2 be2 = *(const f2*)(beA + boff + cb2);

    unsigned* dst0 = (br == 0 ? mq : (br == 1 ? mk : mv));

    f4 vs4_ = f4{0.f, 0.f, 0.f, 0.f};
    f2 vs2_ = f2{0.f, 0.f};

    for (int t = 0; t < T_; ++t) {
        const size_t base = (size_t)(t * B_ + b) * NW_ * N_ + n;
        const unsigned* mp = mask_x + base;
        unsigned bwv[NW_];
#pragma unroll
        for (int w = 0; w < NW_; ++w) bwv[w] = mp[(size_t)w * N_];

        f4 a4 = f4{0.f, 0.f, 0.f, 0.f};
        f2 a2 = f2{0.f, 0.f};

        for (int w = 0; w < NW_; ++w) {
            unsigned bits = __builtin_amdgcn_readfirstlane(bwv[w]);
            const float* wb0 = Wt + (size_t)(w * 32) * M3_ + boff;
            int np = __builtin_popcount(bits);
            for (; np >= 4; np -= 4) {
                int c0 = __builtin_ctz(bits); bits &= bits - 1;
                int c1 = __builtin_ctz(bits); bits &= bits - 1;
                int c2 = __builtin_ctz(bits); bits &= bits - 1;
                int c3 = __builtin_ctz(bits); bits &= bits - 1;
                const float* r0 = wb0 + (size_t)c0 * M3_;
                const float* r1 = wb0 + (size_t)c1 * M3_;
                const float* r2 = wb0 + (size_t)c2 * M3_;
                const float* r3 = wb0 + (size_t)c3 * M3_;
                f4 x0 = *(const f4*)(r0 + cb4); f2 y0 = *(const f2*)(r0 + cb2);
                f4 x1 = *(const f4*)(r1 + cb4); f2 y1 = *(const f2*)(r1 + cb2);
                f4 x2 = *(const f4*)(r2 + cb4); f2 y2 = *(const f2*)(r2 + cb2);
                f4 x3 = *(const f4*)(r3 + cb4); f2 y3 = *(const f2*)(r3 + cb2);
                a4 += x0; a2 += y0;
                a4 += x1; a2 += y1;
                a4 += x2; a2 += y2;
                a4 += x3; a2 += y3;
            }
            for (; np > 0; --np) {
                int c0 = __builtin_ctz(bits); bits &= bits - 1;
                const float* r0 = wb0 + (size_t)c0 * M3_;
                f4 x0 = *(const f4*)(r0 + cb4); f2 y0 = *(const f2*)(r0 + cb2);
                a4 += x0; a2 += y0;
            }
        }

        // BN + LIF + ballots
        unsigned* d = dst0 + base;
        f4 pre4 = (a4 - mu4) * iv4 + be4;
        f4 v24 = vs4_ + (pre4 - vs4_) * 0.5f;
#pragma unroll
        for (int q = 0; q < 4; ++q) {
            bool s = (v24[q] >= 1.0f);
            vs4_[q] = s ? 0.f : v24[q];
            unsigned long long bal = __ballot(s);
            if (lane == 0) {
                d[(size_t)(2 * q) * N_]     = (unsigned)bal;
                d[(size_t)(2 * q + 1) * N_] = (unsigned)(bal >> 32);
            }
        }
        f2 pre2 = (a2 - mu2) * iv2 + be2;
        f2 v22 = vs2_ + (pre2 - vs2_) * 0.5f;
#pragma unroll
        for (int q = 0; q < 2; ++q) {
            bool s = (v22[q] >= 1.0f);
            vs2_[q] = s ? 0.f : v22[q];
            unsigned long long bal = __ballot(s);
            if (lane == 0) {
                d[(size_t)(8 + 2 * q) * N_] = (unsigned)bal;
                d[(size_t)(9 + 2 * q) * N_] = (unsigned)(bal >> 32);
            }
        }
    }
}

// ---------------------------------------------------------------------------
// K4a: per (t,b,storage-idx) count = sum_n k&v  (bit-layout agnostic)
// ---------------------------------------------------------------------------
__global__ __launch_bounds__(384) void kv_count(const unsigned* __restrict__ mk,
                                                const unsigned* __restrict__ mv,
                                                int* __restrict__ cnt) {
    int tb = blockIdx.x;                // t*B_+b
    int w = threadIdx.x >> 5, chunk = threadIdx.x & 31;
    __shared__ int sc[C_];
    if (threadIdx.x < C_) sc[threadIdx.x] = 0;
    __syncthreads();
    const unsigned* kp = mk + ((size_t)tb * NW_ + w) * N_ + chunk * 32;
    const unsigned* vp = mv + ((size_t)tb * NW_ + w) * N_ + chunk * 32;
    int loc[32];
#pragma unroll
    for (int bit = 0; bit < 32; ++bit) loc[bit] = 0;
#pragma unroll
    for (int i = 0; i < 32; ++i) {
        unsigned a = kp[i] & vp[i];
#pragma unroll
        for (int bit = 0; bit < 32; ++bit) loc[bit] += (int)((a >> bit) & 1u);
    }
#pragma unroll
    for (int bit = 0; bit < 32; ++bit)
        if (loc[bit]) atomicAdd(&sc[w * 32 + bit], loc[bit]);
    __syncthreads();
    if (threadIdx.x < C_) cnt[(size_t)tb * C_ + threadIdx.x] = sc[threadIdx.x];
}

// ---------------------------------------------------------------------------
// K4b: LIF over t on counts (v_th=0.5) -> kv words (storage order, aligns
// bit-for-bit with mask words)
// ---------------------------------------------------------------------------
__global__ __launch_bounds__(384) void kv_lif(const int* __restrict__ cnt,
                                              unsigned* __restrict__ kvw) {
    int b = blockIdx.x, c = threadIdx.x;
    float u = 0.f;
    for (int t = 0; t < T_; ++t) {
        float ct = (float)cnt[(size_t)(t * B_ + b) * C_ + c];
        u = u + (ct - u) * 0.5f;
        bool s = (u >= 0.5f);
        u = s ? 0.f : u;
        unsigned long long bal = __ballot(s);
        if ((c & 63) == 0) {
            int wv = c >> 6;   // wave 0..5 -> words 2wv, 2wv+1
            kvw[(size_t)(t * B_ + b) * NW_ + wv * 2]     = (unsigned)bal;
            kvw[(size_t)(t * B_ + b) * NW_ + wv * 2 + 1] = (unsigned)(bal >> 32);
        }
    }
}

// ---------------------------------------------------------------------------
// K5: output 1 — v spikes to head layout [tb][h][n][dd], from mask_v
// (permuted-layout decode: real channel -> (Wb, bit); unchanged — the new
// per-branch scheme is algebraically identical to the old v-branch scheme)
// ---------------------------------------------------------------------------
__global__ __launch_bounds__(256) void v_to_out1(const unsigned* __restrict__ mv,
                                                 float* __restrict__ out1) {
    int tb = blockIdx.y;
    int n0 = blockIdx.x * 128;
    __shared__ unsigned ws_[NW_][128];
    for (int i = threadIdx.x; i < NW_ * 128; i += 256) {
        int w = i >> 7, nn = i & 127;
        ws_[w][nn] = mv[((size_t)tb * NW_ + w) * N_ + n0 + nn];
    }
    __syncthreads();
    float* dst = out1 + (size_t)tb * HEADS_ * N_ * DH_;
    for (int h = 0; h < HEADS_; ++h) {
        float* dh = dst + ((size_t)h * N_ + n0) * DH_;
#pragma unroll
        for (int l = 0; l < 24; ++l) {
            int flat = l * 256 + threadIdx.x;       // 0..6143 (128n x 48dd)
            int nn = flat / DH_, dd = flat - nn * DH_;
            int c = h * DH_ + dd;                   // real v channel
            int Wb, bit;
            if (c < 256) { Wb = 2 * (c & 3) + (c >> 7); bit = (c & 127) >> 2; }
            else { int r = c - 256; Wb = 8 + 2 * (r & 1) + (r >> 6); bit = (r & 63) >> 1; }
            unsigned wd = ws_[Wb][nn];
            dh[flat] = (float)((wd >> bit) & 1u);
        }
    }
}

// ---------------------------------------------------------------------------
// K6: proj sparse GEMM (active = qmask & kv, storage space) + bias + BN +
// identity -> out0. Register accumulation per column; Wtp rows pre-permuted.
// ---------------------------------------------------------------------------
__global__ __launch_bounds__(256) void proj_out0(
        const unsigned* __restrict__ mq, const unsigned* __restrict__ kvw,
        const float* __restrict__ Wtp, const float* __restrict__ pb,
        const float* __restrict__ pg, const float* __restrict__ pbe,
        const float* __restrict__ pm, const float* __restrict__ pv,
        const float* __restrict__ x, float* __restrict__ out0) {
    int tb = blockIdx.y;
    int n0 = blockIdx.x * 64;
    int m0 = blockIdx.z * 128;
    __shared__ float acc[128][65];
    const int lane = threadIdx.x & 63, wv = threadIdx.x >> 6;

    // kv words are uniform over the whole tb -> scalar regs
    unsigned kvr[NW_];
    const unsigned* kvp = kvw + (size_t)tb * NW_;
#pragma unroll
    for (int w = 0; w < NW_; ++w) kvr[w] = kvp[w];

    for (int ci = 0; ci < 16; ++ci) {
        int coln = wv * 16 + ci;
        const unsigned* mp = mq + (size_t)tb * NW_ * N_ + n0 + coln;
        unsigned bw[NW_];
#pragma unroll
        for (int w = 0; w < NW_; ++w) bw[w] = mp[(size_t)w * N_] & kvr[w];

        float a0 = 0.f, a1 = 0.f, b0 = 0.f, b1 = 0.f;
#pragma unroll
        for (int w = 0; w < NW_; ++w) {
            unsigned bits = bw[w];
            while (bits) {
                int cb0 = __builtin_ctz(bits);
                bits &= bits - 1;
                const float* wr0 = Wtp + (size_t)(w * 32 + cb0) * C_ + m0 + lane;
                if (bits) {
                    int cb1 = __builtin_ctz(bits);
                    bits &= bits - 1;
                    const float* wr1 = Wtp + (size_t)(w * 32 + cb1) * C_ + m0 + lane;
                    float x00 = wr0[0], x01 = wr0[64];
                    float x10 = wr1[0], x11 = wr1[64];
                    a0 += x00; a1 += x01;
                    b0 += x10; b1 += x11;
                } else {
                    a0 += wr0[0];
                    a1 += wr0[64];
                }
            }
        }
        acc[lane][coln]      = a0 + b0;
        acc[lane + 64][coln] = a1 + b1;
    }
    __syncthreads();

    const float* xb = x + (size_t)tb * CN_ + (size_t)m0 * N_ + n0;
    float* ob = out0 + (size_t)tb * CN_ + (size_t)m0 * N_ + n0;
    for (int mi = 0; mi < 32; ++mi) {
        int ml = mi * 4 + wv;            // 0..127 local
        int m = m0 + ml;                 // global channel
        float inv = pg[m] / sqrtf(pv[m] + EPS_);
        float cst = (pb[m] - pm[m]) * inv + pbe[m];
        float a = acc[ml][lane];
        ob[(size_t)ml * N_ + lane] = a * inv + cst + xb[(size_t)ml * N_ + lane];
    }
}

// ---------------------------------------------------------------------------
extern "C" void kernel_launch(void* const* d_in, const int* in_sizes, int n_in,
                              void* d_out, int out_size, void* d_ws, size_t ws_size,
                              hipStream_t stream) {
    (void)in_sizes; (void)n_in; (void)out_size; (void)ws_size;
    const float* x      = (const float*)d_in[0];
    const float* q_w    = (const float*)d_in[1];
    const float* q_g    = (const float*)d_in[2];
    const float* q_b    = (const float*)d_in[3];
    const float* q_m    = (const float*)d_in[4];
    const float* q_v    = (const float*)d_in[5];
    const float* k_w    = (const float*)d_in[6];
    const float* k_g    = (const float*)d_in[7];
    const float* k_b    = (const float*)d_in[8];
    const float* k_m    = (const float*)d_in[9];
    const float* k_v    = (const float*)d_in[10];
    const float* v_w    = (const float*)d_in[11];
    const float* v_g    = (const float*)d_in[12];
    const float* v_b    = (const float*)d_in[13];
    const float* v_m    = (const float*)d_in[14];
    const float* v_v    = (const float*)d_in[15];
    const float* proj_w = (const float*)d_in[16];
    const float* proj_b = (const float*)d_in[17];
    const float* p_g    = (const float*)d_in[18];
    const float* p_be   = (const float*)d_in[19];
    const float* p_m    = (const float*)d_in[20];
    const float* p_v    = (const float*)d_in[21];

    float* out0 = (float*)d_out;
    float* out1 = out0 + TBCN_;

    char* p = (char*)d_ws;
    float* Wt_qkv  = (float*)p;    p += (size_t)C_ * M3_ * 4;   // 1.77 MB
    float* Wt_proj = (float*)p;    p += (size_t)C_ * C_ * 4;    // 0.59 MB
    float* invA    = (float*)p;    p += M3_ * 4;
    float* muA     = (float*)p;    p += M3_ * 4;
    float* beA     = (float*)p;    p += M3_ * 4;
    unsigned* mask_x = (unsigned*)p; p += (size_t)T_ * B_ * NW_ * N_ * 4;
    unsigned* mask_q = (unsigned*)p; p += (size_t)T_ * B_ * NW_ * N_ * 4;
    unsigned* mask_k = (unsigned*)p; p += (size_t)T_ * B_ * NW_ * N_ * 4;
    unsigned* mask_v = (unsigned*)p; p += (size_t)T_ * B_ * NW_ * N_ * 4;
    int* cnt       = (int*)p;      p += (size_t)T_ * B_ * C_ * 4;
    unsigned* kvw  = (unsigned*)p; p += (size_t)T_ * B_ * NW_ * 4;

    // prep (weights/BN constants)
    prep_wt_qkv<<<(C_ * C_) / 256, 256, 0, stream>>>(q_w, k_w, v_w, Wt_qkv);
    prep_wt_proj<<<(C_ * C_) / 256, 256, 0, stream>>>(proj_w, Wt_proj);
    prep_bn<<<(M3_ + 255) / 256, 256, 0, stream>>>(q_g, q_b, q_m, q_v,
                                                   k_g, k_b, k_m, k_v,
                                                   v_g, v_b, v_m, v_v,
                                                   invA, muA, beA);

    // 1) shortcut LIF -> xs bitmasks
    lif_x_mask<<<dim3(N_ / 256, NW_, B_), 256, 0, stream>>>(x, mask_x);

    // 2) fused sparse QKV conv + BN + LIF -> q/k/v bitmasks
    //    (branch-split: z = 3, one branch slice per wave)
    qkv_sparse<<<dim3(N_ / 4, B_, 3), 256, 0, stream>>>(mask_x, Wt_qkv,
                                                        invA, muA, beA,
                                                        mask_q, mask_k, mask_v);

    // 3) kv counts + LIF (exact integer path)
    kv_count<<<T_ * B_, 384, 0, stream>>>(mask_k, mask_v, cnt);
    kv_lif<<<B_, 384, 0, stream>>>(cnt, kvw);

    // 4) output 1: v spikes in head layout
    v_to_out1<<<dim3(N_ / 128, T_ * B_), 256, 0, stream>>>(mask_v, out1);

    // 5) proj sparse GEMM + bias + BN + identity -> output 0
    proj_out0<<<dim3(N_ / 64, T_ * B_, 3), 256, 0, stream>>>(
        mask_q, kvw, Wt_proj, proj_b, p_g, p_be, p_m, p_v, x, out0);
}

// Round 5
// 560.512 us; speedup vs baseline: 1.0741x; 1.0741x over previous
//
#include <hip/hip_runtime.h>
#include <math.h>

#define T_ 4
#define B_ 16
#define C_ 384
#define N_ 1024
#define CN_ (C_ * N_)      // 393216
#define BCN_ (B_ * CN_)    // 6291456
#define TBCN_ (T_ * BCN_)  // 25165824
#define HEADS_ 8
#define DH_ 48
#define EPS_ 1e-5f
#define NW_ 12             // 384 bits -> 12 words per column
#define M3_ 1152           // 3*C_

typedef float f4 __attribute__((ext_vector_type(4)));
typedef float f2 __attribute__((ext_vector_type(2)));

// ===========================================================================
// Mask bit-layout (PERMUTED, used for mask_q/mask_k/mask_v, kvw, cnt, Wtp):
// lane l owns channels p = g*256 + 4l + q (g=0..3, q=0..3) and
//                      p = 1024 + 2l + q (g=4, q=0..1)   [p = 0..1151 over qkv]
// Ballot (g,q) -> 64 bits; lo/hi 32-bit words stored at (branch, word):
//   g=0: lo (q,0,2q)   hi (q,0,2q+1)      [branch 0 = q]
//   g=1: lo (q,0,8+q)  hi (k,1,q)
//   g=2: lo (k,1,4+2q) hi (k,1,5+2q)
//   g=3: lo (v,2,2q)   hi (v,2,2q+1)
//   g=4: lo (v,2,8+2q) hi (v,2,9+2q)
// Real channel for (word Wb, bit i), q-branch (used by prep_wt_proj):
//   Wb<8 : c = 128*(Wb&1) + 4*i + (Wb>>1)
//   Wb>=8: c = 256 + 4*i + (Wb-8)
// Real channel -> (Wb, bit) for v-branch (used by v_to_out1):
//   c<256 : Wb = 2*(c&3) + (c>>7),      bit = (c&127)>>2
//   c>=256: r=c-256; Wb = 8+2*(r&1)+(r>>6), bit = (r&63)>>1
// mask_x (input side) keeps the plain layout: word w, bit i <-> c = 32w+i.
// ===========================================================================

// ---------------------------------------------------------------------------
// P1: Wt_qkv[c][br*384+m] = W_br[m][c]   (concat q,k,v, transposed)
// ---------------------------------------------------------------------------
__global__ __launch_bounds__(256) void prep_wt_qkv(
        const float* __restrict__ qw, const float* __restrict__ kw,
        const float* __restrict__ vw, float* __restrict__ Wt) {
    int idx = blockIdx.x * 256 + threadIdx.x;  // over 384*384
    int m = idx / C_, c = idx % C_;
    Wt[(size_t)c * M3_ + m]       = qw[idx];
    Wt[(size_t)c * M3_ + 384 + m] = kw[idx];
    Wt[(size_t)c * M3_ + 768 + m] = vw[idx];
}

// Wtp rows in PERMUTED q-storage order: row r holds proj_w[:, creal(r)]^T
__global__ __launch_bounds__(256) void prep_wt_proj(
        const float* __restrict__ pw, float* __restrict__ Wtp) {
    int idx = blockIdx.x * 256 + threadIdx.x;   // over 384*384
    int r = idx / C_, m = idx % C_;
    int Wb = r >> 5, i = r & 31;
    int c = (Wb < 8) ? (128 * (Wb & 1) + 4 * i + (Wb >> 1))
                     : (256 + 4 * i + (Wb - 8));
    Wtp[(size_t)r * C_ + m] = pw[(size_t)m * C_ + c];
}

// ---------------------------------------------------------------------------
// P2: per-m' BN constants for qkv branches (inv computed exactly as reference)
// ---------------------------------------------------------------------------
__global__ __launch_bounds__(256) void prep_bn(
        const float* __restrict__ qg, const float* __restrict__ qb,
        const float* __restrict__ qm, const float* __restrict__ qv,
        const float* __restrict__ kg, const float* __restrict__ kb,
        const float* __restrict__ km, const float* __restrict__ kv2,
        const float* __restrict__ vg, const float* __restrict__ vb,
        const float* __restrict__ vm, const float* __restrict__ vv,
        float* __restrict__ invA, float* __restrict__ muA, float* __restrict__ beA) {
    int i = blockIdx.x * 256 + threadIdx.x;
    if (i >= M3_) return;
    int br = i / C_, c = i % C_;
    const float *g, *bb, *mm, *va;
    if (br == 0)      { g = qg; bb = qb; mm = qm; va = qv; }
    else if (br == 1) { g = kg; bb = kb; mm = km; va = kv2; }
    else              { g = vg; bb = vb; mm = vm; va = vv; }
    invA[i] = g[c] / sqrtf(va[c] + EPS_);
    muA[i]  = mm[c];
    beA[i]  = bb[c];
}

// ---------------------------------------------------------------------------
// K1: shortcut LIF on x -> column bitmasks  mask_x[t][b][w][n]  (plain layout)
// ---------------------------------------------------------------------------
__global__ __launch_bounds__(256) void lif_x_mask(const float* __restrict__ x,
                                                  unsigned* __restrict__ mask_x) {
    int n  = blockIdx.x * 256 + threadIdx.x;
    int cw = blockIdx.y;   // 0..11
    int b  = blockIdx.z;   // 0..15
    unsigned wrd[T_] = {0u, 0u, 0u, 0u};
    const float* xb = x + (size_t)b * CN_ + (size_t)cw * 32 * N_ + n;
#pragma unroll 4
    for (int cb = 0; cb < 32; ++cb) {
        const float* xp = xb + (size_t)cb * N_;
        float v = 0.f;
#pragma unroll
        for (int t = 0; t < T_; ++t) {
            float xt = xp[(size_t)t * BCN_];
            v = v + (xt - v) * 0.5f;   // == v + (x - v)/2 exactly
            if (v >= 1.0f) { wrd[t] |= (1u << cb); v = 0.f; }
        }
    }
#pragma unroll
    for (int t = 0; t < T_; ++t)
        mask_x[((size_t)(t * B_ + b) * NW_ + cw) * N_ + n] = wrd[t];
}

// ---------------------------------------------------------------------------
// K3: fused sparse QKV GEMM + BN + LIF -> spike bitmasks (permuted layout)
// wave per column (b,n); lane owns 18 contiguous-channel slots (4xf4 + 1xf2).
// Per active bit: 5 vector loads (4x dwordx4 + 1x dwordx2); 2 bits in flight.
// NOTE: no min-waves clamp — the loop needs ~110 VGPRs; forcing 64 (round 2)
// spilled the accumulators to scratch (FETCH 19->301MB, WRITE 30->224MB).
// This structure is at the per-CU VMEM return-path floor (~180 us); round-3
// (5 vec loads) and round-1 (18 scalar loads) time identical, branch-split
// (round 4) regressed. Do not re-split.
// ---------------------------------------------------------------------------
__global__ __launch_bounds__(256) void qkv_sparse(
        const unsigned* __restrict__ mask_x, const float* __restrict__ Wt,
        const float* __restrict__ invA, const float* __restrict__ muA,
        const float* __restrict__ beA,
        unsigned* __restrict__ mq, unsigned* __restrict__ mk,
        unsigned* __restrict__ mv) {
    const int lane = threadIdx.x & 63;
    const int col  = threadIdx.x >> 6;   // 0..3
    const int n = blockIdx.x * 4 + col;
    const int b = blockIdx.y;

    f4 vs[4] = {f4{0.f,0.f,0.f,0.f}, f4{0.f,0.f,0.f,0.f},
                f4{0.f,0.f,0.f,0.f}, f4{0.f,0.f,0.f,0.f}};
    f2 vs4 = f2{0.f, 0.f};

    for (int t = 0; t < T_; ++t) {
        const size_t base = (size_t)(t * B_ + b) * NW_ * N_ + n;
        const unsigned* mp = mask_x + base;
        // prefetch all 12 mask words (issued together)
        unsigned bwv[NW_];
#pragma unroll
        for (int w = 0; w < NW_; ++w) bwv[w] = mp[(size_t)w * N_];

        f4 acc[4] = {f4{0.f,0.f,0.f,0.f}, f4{0.f,0.f,0.f,0.f},
                     f4{0.f,0.f,0.f,0.f}, f4{0.f,0.f,0.f,0.f}};
        f2 acc4 = f2{0.f, 0.f};

        for (int w = 0; w < NW_; ++w) {
            unsigned bits = __builtin_amdgcn_readfirstlane(bwv[w]);
            const float* wb0 = Wt + (size_t)(w * 32) * M3_;
            while (bits) {
                int cb0 = __builtin_ctz(bits); bits &= bits - 1;
                const float* r0 = wb0 + (size_t)cb0 * M3_;
                f4 d00 = *(const f4*)(r0 + 4 * lane);
                f4 d01 = *(const f4*)(r0 + 256 + 4 * lane);
                f4 d02 = *(const f4*)(r0 + 512 + 4 * lane);
                f4 d03 = *(const f4*)(r0 + 768 + 4 * lane);
                f2 d04 = *(const f2*)(r0 + 1024 + 2 * lane);
                if (bits) {
                    int cb1 = __builtin_ctz(bits); bits &= bits - 1;
                    const float* r1 = wb0 + (size_t)cb1 * M3_;
                    f4 d10 = *(const f4*)(r1 + 4 * lane);
                    f4 d11 = *(const f4*)(r1 + 256 + 4 * lane);
                    f4 d12 = *(const f4*)(r1 + 512 + 4 * lane);
                    f4 d13 = *(const f4*)(r1 + 768 + 4 * lane);
                    f2 d14 = *(const f2*)(r1 + 1024 + 2 * lane);
                    acc[0] += d00; acc[1] += d01; acc[2] += d02; acc[3] += d03;
                    acc4 += d04;
                    acc[0] += d10; acc[1] += d11; acc[2] += d12; acc[3] += d13;
                    acc4 += d14;
                } else {
                    acc[0] += d00; acc[1] += d01; acc[2] += d02; acc[3] += d03;
                    acc4 += d04;
                }
            }
        }

        // BN + LIF + ballots (permuted word layout, see table at top)
        unsigned* dq = mq + base;
        unsigned* dk = mk + base;
        unsigned* dv = mv + base;
#pragma unroll
        for (int g = 0; g < 4; ++g) {
            f4 iv = *(const f4*)(invA + g * 256 + 4 * lane);
            f4 mu = *(const f4*)(muA + g * 256 + 4 * lane);
            f4 be = *(const f4*)(beA + g * 256 + 4 * lane);
            f4 pre = (acc[g] - mu) * iv + be;
            f4 v2 = vs[g] + (pre - vs[g]) * 0.5f;
#pragma unroll
            for (int q = 0; q < 4; ++q) {
                bool s = (v2[q] >= 1.0f);
                vs[g][q] = s ? 0.f : v2[q];
                unsigned long long bal = __ballot(s);
                if (lane == 0) {
                    unsigned lo = (unsigned)bal, hi = (unsigned)(bal >> 32);
                    if (g == 0) {
                        dq[(size_t)(2 * q) * N_] = lo;
                        dq[(size_t)(2 * q + 1) * N_] = hi;
                    } else if (g == 1) {
                        dq[(size_t)(8 + q) * N_] = lo;
                        dk[(size_t)q * N_] = hi;
                    } else if (g == 2) {
                        dk[(size_t)(4 + 2 * q) * N_] = lo;
                        dk[(size_t)(5 + 2 * q) * N_] = hi;
                    } else {
                        dv[(size_t)(2 * q) * N_] = lo;
                        dv[(size_t)(2 * q + 1) * N_] = hi;
                    }
                }
            }
        }
        {
            f2 iv = *(const f2*)(invA + 1024 + 2 * lane);
            f2 mu = *(const f2*)(muA + 1024 + 2 * lane);
            f2 be = *(const f2*)(beA + 1024 + 2 * lane);
            f2 pre = (acc4 - mu) * iv + be;
            f2 v2 = vs4 + (pre - vs4) * 0.5f;
#pragma unroll
            for (int q = 0; q < 2; ++q) {
                bool s = (v2[q] >= 1.0f);
                vs4[q] = s ? 0.f : v2[q];
                unsigned long long bal = __ballot(s);
                if (lane == 0) {
                    dv[(size_t)(8 + 2 * q) * N_] = (unsigned)bal;
                    dv[(size_t)(9 + 2 * q) * N_] = (unsigned)(bal >> 32);
                }
            }
        }
    }
}

// ---------------------------------------------------------------------------
// K4a: per (t,b,storage-idx) count = sum_n k&v  (bit-layout agnostic)
// ---------------------------------------------------------------------------
__global__ __launch_bounds__(384) void kv_count(const unsigned* __restrict__ mk,
                                                const unsigned* __restrict__ mv,
                                                int* __restrict__ cnt) {
    int tb = blockIdx.x;                // t*B_+b
    int w = threadIdx.x >> 5, chunk = threadIdx.x & 31;
    __shared__ int sc[C_];
    if (threadIdx.x < C_) sc[threadIdx.x] = 0;
    __syncthreads();
    const unsigned* kp = mk + ((size_t)tb * NW_ + w) * N_ + chunk * 32;
    const unsigned* vp = mv + ((size_t)tb * NW_ + w) * N_ + chunk * 32;
    int loc[32];
#pragma unroll
    for (int bit = 0; bit < 32; ++bit) loc[bit] = 0;
#pragma unroll
    for (int i = 0; i < 32; ++i) {
        unsigned a = kp[i] & vp[i];
#pragma unroll
        for (int bit = 0; bit < 32; ++bit) loc[bit] += (int)((a >> bit) & 1u);
    }
#pragma unroll
    for (int bit = 0; bit < 32; ++bit)
        if (loc[bit]) atomicAdd(&sc[w * 32 + bit], loc[bit]);
    __syncthreads();
    if (threadIdx.x < C_) cnt[(size_t)tb * C_ + threadIdx.x] = sc[threadIdx.x];
}

// ---------------------------------------------------------------------------
// K4b: LIF over t on counts (v_th=0.5) -> kv words (storage order, aligns
// bit-for-bit with mask words)
// ---------------------------------------------------------------------------
__global__ __launch_bounds__(384) void kv_lif(const int* __restrict__ cnt,
                                              unsigned* __restrict__ kvw) {
    int b = blockIdx.x, c = threadIdx.x;
    float u = 0.f;
    for (int t = 0; t < T_; ++t) {
        float ct = (float)cnt[(size_t)(t * B_ + b) * C_ + c];
        u = u + (ct - u) * 0.5f;
        bool s = (u >= 0.5f);
        u = s ? 0.f : u;
        unsigned long long bal = __ballot(s);
        if ((c & 63) == 0) {
            int wv = c >> 6;   // wave 0..5 -> words 2wv, 2wv+1
            kvw[(size_t)(t * B_ + b) * NW_ + wv * 2]     = (unsigned)bal;
            kvw[(size_t)(t * B_ + b) * NW_ + wv * 2 + 1] = (unsigned)(bal >> 32);
        }
    }
}

// ---------------------------------------------------------------------------
// K5: output 1 — v spikes to head layout [tb][h][n][dd], from mask_v
// (permuted-layout decode; float4 stores: 1536 f4 per (h, n0-tile))
// ---------------------------------------------------------------------------
__global__ __launch_bounds__(256) void v_to_out1(const unsigned* __restrict__ mv,
                                                 float* __restrict__ out1) {
    int tb = blockIdx.y;
    int n0 = blockIdx.x * 128;
    __shared__ unsigned ws_[NW_][128];
    for (int i = threadIdx.x; i < NW_ * 128; i += 256) {
        int w = i >> 7, nn = i & 127;
        ws_[w][nn] = mv[((size_t)tb * NW_ + w) * N_ + n0 + nn];
    }
    __syncthreads();
    float* dst = out1 + (size_t)tb * HEADS_ * N_ * DH_;
    for (int h = 0; h < HEADS_; ++h) {
        f4* dh4 = (f4*)(dst + ((size_t)h * N_ + n0) * DH_);
#pragma unroll
        for (int l = 0; l < 6; ++l) {
            int f4id = l * 256 + threadIdx.x;      // 0..1535 (128n x 12 f4)
            int nn = f4id / 12, dq = f4id - nn * 12;
            int dd0 = dq * 4;
            f4 o;
#pragma unroll
            for (int j = 0; j < 4; ++j) {
                int c = h * DH_ + dd0 + j;          // real v channel
                int Wb, bit;
                if (c < 256) { Wb = 2 * (c & 3) + (c >> 7); bit = (c & 127) >> 2; }
                else { int r = c - 256; Wb = 8 + 2 * (r & 1) + (r >> 6); bit = (r & 63) >> 1; }
                o[j] = (float)((ws_[Wb][nn] >> bit) & 1u);
            }
            dh4[f4id] = o;
        }
    }
}

// ---------------------------------------------------------------------------
// K5b: build per-column compact index lists for proj: active = mq & kvw.
// qlist[tb][n][0..cnt) = storage row indices (u8), qcnt[tb][n] = count.
// ---------------------------------------------------------------------------
__global__ __launch_bounds__(256) void build_qlist(
        const unsigned* __restrict__ mq, const unsigned* __restrict__ kvw,
        unsigned char* __restrict__ qlist, int* __restrict__ qcnt) {
    int n = blockIdx.x * 256 + threadIdx.x;  // 0..1023
    int tb = blockIdx.y;                     // 0..63
    const unsigned* mp = mq + (size_t)tb * NW_ * N_ + n;
    const unsigned* kvp = kvw + (size_t)tb * NW_;
    unsigned char* dst = qlist + ((size_t)tb * N_ + n) * C_;
    int cnt = 0;
    for (int w = 0; w < NW_; ++w) {
        unsigned bits = mp[(size_t)w * N_] & kvp[w];
        int base = w * 32;
        while (bits) {
            int cb = __builtin_ctz(bits);
            bits &= bits - 1;
            dst[cnt++] = (unsigned char)(base + cb);
        }
    }
    qcnt[(size_t)tb * N_ + n] = cnt;
}

// ---------------------------------------------------------------------------
// K6: proj sparse GEMM via compact lists + bias + BN + identity -> out0.
// Per column: uniform u32 load of 4 packed row indices -> 8 weight loads in
// flight -> 8 independent adds (4 acc pairs). Register accumulation; LDS
// transpose for coalesced out0 writes.
// ---------------------------------------------------------------------------
__global__ __launch_bounds__(256) void proj_out0(
        const unsigned char* __restrict__ qlist, const int* __restrict__ qcnt,
        const float* __restrict__ Wtp, const float* __restrict__ pb,
        const float* __restrict__ pg, const float* __restrict__ pbe,
        const float* __restrict__ pm, const float* __restrict__ pv,
        const float* __restrict__ x, float* __restrict__ out0) {
    int tb = blockIdx.y;
    int n0 = blockIdx.x * 64;
    int m0 = blockIdx.z * 128;
    __shared__ float acc[128][65];
    const int lane = threadIdx.x & 63, wv = threadIdx.x >> 6;

    for (int ci = 0; ci < 16; ++ci) {
        int coln = wv * 16 + ci;
        int col = n0 + coln;
        int cnt = qcnt[(size_t)tb * N_ + col];
        const unsigned char* lst = qlist + ((size_t)tb * N_ + col) * C_;
        const float* Wb = Wtp + m0 + lane;

        float a0 = 0.f, a1 = 0.f, b0 = 0.f, b1 = 0.f;
        float c0 = 0.f, c1 = 0.f, d0 = 0.f, d1 = 0.f;
        int i = 0;
        for (; i + 4 <= cnt; i += 4) {
            unsigned pk = *(const unsigned*)(lst + i);
            const float* w0 = Wb + (size_t)(pk & 255u) * C_;
            const float* w1 = Wb + (size_t)((pk >> 8) & 255u) * C_;
            const float* w2 = Wb + (size_t)((pk >> 16) & 255u) * C_;
            const float* w3 = Wb + (size_t)(pk >> 24) * C_;
            float x00 = w0[0], x01 = w0[64];
            float x10 = w1[0], x11 = w1[64];
            float x20 = w2[0], x21 = w2[64];
            float x30 = w3[0], x31 = w3[64];
            a0 += x00; a1 += x01; b0 += x10; b1 += x11;
            c0 += x20; c1 += x21; d0 += x30; d1 += x31;
        }
        for (; i < cnt; ++i) {
            const float* w0 = Wb + (size_t)lst[i] * C_;
            a0 += w0[0]; a1 += w0[64];
        }
        acc[lane][coln]      = (a0 + b0) + (c0 + d0);
        acc[lane + 64][coln] = (a1 + b1) + (c1 + d1);
    }
    __syncthreads();

    const float* xb = x + (size_t)tb * CN_ + (size_t)m0 * N_ + n0;
    float* ob = out0 + (size_t)tb * CN_ + (size_t)m0 * N_ + n0;
    for (int mi = 0; mi < 32; ++mi) {
        int ml = mi * 4 + wv;            // 0..127 local
        int m = m0 + ml;                 // global channel
        float inv = pg[m] / sqrtf(pv[m] + EPS_);
        float cst = (pb[m] - pm[m]) * inv + pbe[m];
        float a = acc[ml][lane];
        ob[(size_t)ml * N_ + lane] = a * inv + cst + xb[(size_t)ml * N_ + lane];
    }
}

// ---------------------------------------------------------------------------
// K6-fallback: bitscan proj (round-3 version) for when ws is too small for
// the qlist buffers.
// ---------------------------------------------------------------------------
__global__ __launch_bounds__(256) void proj_out0_bits(
        const unsigned* __restrict__ mq, const unsigned* __restrict__ kvw,
        const float* __restrict__ Wtp, const float* __restrict__ pb,
        const float* __restrict__ pg, const float* __restrict__ pbe,
        const float* __restrict__ pm, const float* __restrict__ pv,
        const float* __restrict__ x, float* __restrict__ out0) {
    int tb = blockIdx.y;
    int n0 = blockIdx.x * 64;
    int m0 = blockIdx.z * 128;
    __shared__ float acc[128][65];
    const int lane = threadIdx.x & 63, wv = threadIdx.x >> 6;

    unsigned kvr[NW_];
    const unsigned* kvp = kvw + (size_t)tb * NW_;
#pragma unroll
    for (int w = 0; w < NW_; ++w) kvr[w] = kvp[w];

    for (int ci = 0; ci < 16; ++ci) {
        int coln = wv * 16 + ci;
        const unsigned* mp = mq + (size_t)tb * NW_ * N_ + n0 + coln;
        unsigned bw[NW_];
#pragma unroll
        for (int w = 0; w < NW_; ++w) bw[w] = mp[(size_t)w * N_] & kvr[w];

        float a0 = 0.f, a1 = 0.f, b0 = 0.f, b1 = 0.f;
#pragma unroll
        for (int w = 0; w < NW_; ++w) {
            unsigned bits = bw[w];
            while (bits) {
                int cb0 = __builtin_ctz(bits);
                bits &= bits - 1;
                const float* wr0 = Wtp + (size_t)(w * 32 + cb0) * C_ + m0 + lane;
                if (bits) {
                    int cb1 = __builtin_ctz(bits);
                    bits &= bits - 1;
                    const float* wr1 = Wtp + (size_t)(w * 32 + cb1) * C_ + m0 + lane;
                    float x00 = wr0[0], x01 = wr0[64];
                    float x10 = wr1[0], x11 = wr1[64];
                    a0 += x00; a1 += x01;
                    b0 += x10; b1 += x11;
                } else {
                    a0 += wr0[0];
                    a1 += wr0[64];
                }
            }
        }
        acc[lane][coln]      = a0 + b0;
        acc[lane + 64][coln] = a1 + b1;
    }
    __syncthreads();

    const float* xb = x + (size_t)tb * CN_ + (size_t)m0 * N_ + n0;
    float* ob = out0 + (size_t)tb * CN_ + (size_t)m0 * N_ + n0;
    for (int mi = 0; mi < 32; ++mi) {
        int ml = mi * 4 + wv;
        int m = m0 + ml;
        float inv = pg[m] / sqrtf(pv[m] + EPS_);
        float cst = (pb[m] - pm[m]) * inv + pbe[m];
        float a = acc[ml][lane];
        ob[(size_t)ml * N_ + lane] = a * inv + cst + xb[(size_t)ml * N_ + lane];
    }
}

// ---------------------------------------------------------------------------
extern "C" void kernel_launch(void* const* d_in, const int* in_sizes, int n_in,
                              void* d_out, int out_size, void* d_ws, size_t ws_size,
                              hipStream_t stream) {
    (void)in_sizes; (void)n_in; (void)out_size;
    const float* x      = (const float*)d_in[0];
    const float* q_w    = (const float*)d_in[1];
    const float* q_g    = (const float*)d_in[2];
    const float* q_b    = (const float*)d_in[3];
    const float* q_m    = (const float*)d_in[4];
    const float* q_v    = (const float*)d_in[5];
    const float* k_w    = (const float*)d_in[6];
    const float* k_g    = (const float*)d_in[7];
    const float* k_b    = (const float*)d_in[8];
    const float* k_m    = (const float*)d_in[9];
    const float* k_v    = (const float*)d_in[10];
    const float* v_w    = (const float*)d_in[11];
    const float* v_g    = (const float*)d_in[12];
    const float* v_b    = (const float*)d_in[13];
    const float* v_m    = (const float*)d_in[14];
    const float* v_v    = (const float*)d_in[15];
    const float* proj_w = (const float*)d_in[16];
    const float* proj_b = (const float*)d_in[17];
    const float* p_g    = (const float*)d_in[18];
    const float* p_be   = (const float*)d_in[19];
    const float* p_m    = (const float*)d_in[20];
    const float* p_v    = (const float*)d_in[21];

    float* out0 = (float*)d_out;
    float* out1 = out0 + TBCN_;

    char* p = (char*)d_ws;
    float* Wt_qkv  = (float*)p;    p += (size_t)C_ * M3_ * 4;   // 1.77 MB
    float* Wt_proj = (float*)p;    p += (size_t)C_ * C_ * 4;    // 0.59 MB
    float* invA    = (float*)p;    p += M3_ * 4;
    float* muA     = (float*)p;    p += M3_ * 4;
    float* beA     = (float*)p;    p += M3_ * 4;
    unsigned* mask_x = (unsigned*)p; p += (size_t)T_ * B_ * NW_ * N_ * 4;
    unsigned* mask_q = (unsigned*)p; p += (size_t)T_ * B_ * NW_ * N_ * 4;
    unsigned* mask_k = (unsigned*)p; p += (size_t)T_ * B_ * NW_ * N_ * 4;
    unsigned* mask_v = (unsigned*)p; p += (size_t)T_ * B_ * NW_ * N_ * 4;
    int* cnt       = (int*)p;      p += (size_t)T_ * B_ * C_ * 4;
    unsigned* kvw  = (unsigned*)p; p += (size_t)T_ * B_ * NW_ * 4;
    int* qcnt      = (int*)p;      p += (size_t)T_ * B_ * N_ * 4;   // 256 KB
    unsigned char* qlist = (unsigned char*)p;
    p += (size_t)T_ * B_ * N_ * C_;                                  // 25.2 MB
    const int use_list = (ws_size == 0) ? 0
                         : (ws_size >= (size_t)(p - (char*)d_ws) ? 1 : 0);

    // prep (weights/BN constants)
    prep_wt_qkv<<<(C_ * C_) / 256, 256, 0, stream>>>(q_w, k_w, v_w, Wt_qkv);
    prep_wt_proj<<<(C_ * C_) / 256, 256, 0, stream>>>(proj_w, Wt_proj);
    prep_bn<<<(M3_ + 255) / 256, 256, 0, stream>>>(q_g, q_b, q_m, q_v,
                                                   k_g, k_b, k_m, k_v,
                                                   v_g, v_b, v_m, v_v,
                                                   invA, muA, beA);

    // 1) shortcut LIF -> xs bitmasks
    lif_x_mask<<<dim3(N_ / 256, NW_, B_), 256, 0, stream>>>(x, mask_x);

    // 2) fused sparse QKV conv + BN + LIF -> q/k/v bitmasks
    qkv_sparse<<<dim3(N_ / 4, B_), 256, 0, stream>>>(mask_x, Wt_qkv,
                                                     invA, muA, beA,
                                                     mask_q, mask_k, mask_v);

    // 3) kv counts + LIF (exact integer path)
    kv_count<<<T_ * B_, 384, 0, stream>>>(mask_k, mask_v, cnt);
    kv_lif<<<B_, 384, 0, stream>>>(cnt, kvw);

    // 4) output 1: v spikes in head layout
    v_to_out1<<<dim3(N_ / 128, T_ * B_), 256, 0, stream>>>(mask_v, out1);

    // 5) proj sparse GEMM + bias + BN + identity -> output 0
    if (use_list) {
        build_qlist<<<dim3(N_ / 256, T_ * B_), 256, 0, stream>>>(mask_q, kvw,
                                                                 qlist, qcnt);
        proj_out0<<<dim3(N_ / 64, T_ * B_, 3), 256, 0, stream>>>(
            qlist, qcnt, Wt_proj, proj_b, p_g, p_be, p_m, p_v, x, out0);
    } else {
        proj_out0_bits<<<dim3(N_ / 64, T_ * B_, 3), 256, 0, stream>>>(
            mask_q, kvw, Wt_proj, proj_b, p_g, p_be, p_m, p_v, x, out0);
    }
}